// Round 1
// baseline (292.432 us; speedup 1.0000x reference)
//
#include <hip/hip_runtime.h>
#include <cstdint>
#include <cstddef>

// Problem constants: B=8, S=2048, H=512, M=4096 -> R = B*S = 16384 rows.
#define H_DIM   512
#define M_DIM   4096

typedef unsigned short u16;
typedef short bf16x8 __attribute__((ext_vector_type(8)));   // 8 bf16 in 4 VGPRs
typedef float f32x4  __attribute__((ext_vector_type(4)));

// fp32 -> bf16 round-to-nearest-even
__device__ __forceinline__ u16 f2b(float f) {
  union { float f; uint32_t u; } v; v.f = f;
  uint32_t u = v.u + (0x7FFFu + ((v.u >> 16) & 1u));
  return (u16)(u >> 16);
}

// ---------------- elementwise fp32 -> bf16 (n4 = n/4 float4 groups) ----------
__global__ void k_f2bf(const float* __restrict__ in, u16* __restrict__ out, int n4) {
  int i = blockIdx.x * blockDim.x + threadIdx.x;
  if (i < n4) {
    float4 v = ((const float4*)in)[i];
    ushort4 o;
    o.x = f2b(v.x); o.y = f2b(v.y); o.z = f2b(v.z); o.w = f2b(v.w);
    ((ushort4*)out)[i] = o;
  }
}

// ---- both weight casts in one launch: 512 blocks x 256 thr, 2x 65536 f4 -----
__global__ void k_f2bf_ww(const float* __restrict__ wk, const float* __restrict__ wo,
                          u16* __restrict__ owk, u16* __restrict__ owo) {
  int i = blockIdx.x * blockDim.x + threadIdx.x;
  const float* src = (i < 65536) ? wk : wo;
  u16* dst = (i < 65536) ? owk : owo;
  int j = i & 65535;
  float4 v = ((const float4*)src)[j];
  ushort4 o;
  o.x = f2b(v.x); o.y = f2b(v.y); o.z = f2b(v.z); o.w = f2b(v.w);
  ((ushort4*)dst)[j] = o;
}

// ---- compaction: scan usage[4096] -> idx map + meta -------------------------
// meta[0]=count, meta[1]=K_eff=round128(count), meta[2]=K_eff/32, meta[3]=K_eff/128
__global__ void k_compact(const int* __restrict__ usage, int* __restrict__ idx,
                          int* __restrict__ meta) {
  __shared__ int cnt[256];
  int t = threadIdx.x;
  int base = t * 16;
  int c = 0;
  #pragma unroll
  for (int i = 0; i < 16; ++i) c += (usage[base + i] > 0) ? 1 : 0;
  cnt[t] = c;
  __syncthreads();
  for (int d = 1; d < 256; d <<= 1) {           // inclusive Hillis-Steele scan
    int v = (t >= d) ? cnt[t - d] : 0;
    __syncthreads();
    cnt[t] += v;
    __syncthreads();
  }
  int pos = cnt[t] - c;                          // exclusive prefix
  for (int i = 0; i < 16; ++i)
    if (usage[base + i] > 0) idx[pos++] = base + i;
  if (t == 0) {
    int total = cnt[255];
    int keff = ((total + 127) >> 7) << 7;        // 128-granular padding
    meta[0] = total; meta[1] = keff; meta[2] = keff >> 5; meta[3] = keff >> 7;
  }
}

// ---- gather both: keys (L2-normalized) AND vals (plain) -> compacted bf16 ---
__global__ void k_gather_both(const float* __restrict__ keys, const float* __restrict__ vals,
                              const int* __restrict__ idx, const int* __restrict__ meta,
                              u16* __restrict__ okeys, u16* __restrict__ ovals) {
  int j    = blockIdx.x * 4 + (threadIdx.x >> 6);
  int lane = threadIdx.x & 63;
  int count = meta[0];
  ushort4* kp = (ushort4*)(okeys + (size_t)j * H_DIM);
  ushort4* vp = (ushort4*)(ovals + (size_t)j * H_DIM);
  if (j >= count) {                 // wave-uniform
    ushort4 z = {0, 0, 0, 0};
    kp[lane] = z; kp[lane + 64] = z;
    vp[lane] = z; vp[lane + 64] = z;
    return;
  }
  int src = idx[j];
  // keys: normalize
  const float4* rp = (const float4*)(keys + (size_t)src * H_DIM);
  float4 a = rp[lane];
  float4 b = rp[lane + 64];
  float ss = a.x*a.x + a.y*a.y + a.z*a.z + a.w*a.w
           + b.x*b.x + b.y*b.y + b.z*b.z + b.w*b.w;
  #pragma unroll
  for (int d = 1; d < 64; d <<= 1) ss += __shfl_xor(ss, d, 64);
  float s = rsqrtf(ss + 1e-6f);
  ushort4 oa, ob;
  oa.x = f2b(a.x*s); oa.y = f2b(a.y*s); oa.z = f2b(a.z*s); oa.w = f2b(a.w*s);
  ob.x = f2b(b.x*s); ob.y = f2b(b.y*s); ob.z = f2b(b.z*s); ob.w = f2b(b.w*s);
  kp[lane]      = oa;
  kp[lane + 64] = ob;
  // vals: plain cast
  const float4* vr = (const float4*)(vals + (size_t)src * H_DIM);
  float4 c0 = vr[lane];
  float4 c1 = vr[lane + 64];
  ushort4 va, vb;
  va.x = f2b(c0.x); va.y = f2b(c0.y); va.z = f2b(c0.z); va.w = f2b(c0.w);
  vb.x = f2b(c1.x); vb.y = f2b(c1.y); vb.z = f2b(c1.z); vb.w = f2b(c1.w);
  vp[lane]      = va;
  vp[lane + 64] = vb;
}

// ---- rsqQ[r] = rsqrt(sum of 8 qss partials + eps) ---------------------------
__global__ void k_rsq(const float* __restrict__ qss, float* __restrict__ rsq) {
  int r = blockIdx.x * blockDim.x + threadIdx.x;
  float s = 0.0f;
  #pragma unroll
  for (int i = 0; i < 8; ++i) s += qss[(size_t)r * 8 + i];
  rsq[r] = rsqrtf(s + 1e-6f);
}

// ---- reduce partial row sums -> reciprocal (n = meta[1]/64 64-chunks) -------
__global__ void k_reduce_l(const float* __restrict__ lpart, float* __restrict__ linv,
                           const int* __restrict__ meta) {
  int r = blockIdx.x * blockDim.x + threadIdx.x;
  int n = meta[1] >> 6;
  float s = 0.0f;
  for (int i = 0; i < n; ++i) s += lpart[(size_t)r * 64 + i];
  linv[r] = 1.0f / s;
}

// =============================================================================
// BT-layout GEMM: C[row,col] = sum_k A[row,k] * B[col,k]
// 128x128 tile, BK=32, 256 threads = 4 waves; wave w: rows (w>>1)*64, cols
// (w&1)*64; 16x16x32 MFMA, acc[4][4].  Conflict-free LDS: 16-row slab stored
// [chunk(4)][row(16)][8]; lane -> (row=lane&15, chunk=lane>>4).
//
// REGISTER-STAGED SINGLE-BARRIER DOUBLE BUFFER (unchanged, verified core).
//
// __launch_bounds__(256,3): previous build was 108 VGPR + 64 AccVGPR = 172
// total -> only 2 waves/EU (2 blocks/CU).  Forcing 3 waves/EU (<=168 total)
// gives 3 blocks/CU = +50% resident waves to hide the per-iter staged-load
// latency + barrier convoy.  Staged-load addresses are 32-bit byte offsets
// off a shared base to cut address VGPRs (max offset 134 MB < 4 GB).
//
// OPERAND-SWAPPED EPILOGUES: for EPI_QPROJ and EPI_P the REDUCTION axis
// (k resp. m) is placed on the C-tile ROW side (row=(lane>>4)*4+reg), so the
// 4 regs of each f32x4 fragment are 4 consecutive k/m:
//   - packed ushort4 (8B) stores directly into the row-major [r][k] / [r][m]
//     layout the next GEMM consumes (vs 64 scalar 2B stores)
//   - per-column reductions (sumsq / rowsum) are in-register sums over
//     16 values + 2 shuffles (vs 4 shuffles per element + LDS atomics)
//
// EPI_QPROJ: C[k,r] = Wk.hb^T; qb[r][k] = C+bk[k] bf16; sumsq -> aux[r*8+slot]
// EPI_MW   : C[h,m]; MWt[h][m] bf16  (cb-loop over meta[1]/128, step 16)
// EPI_P    : C[m,r] = mkn.qb^T, XCD-swizzled r-block; P[r][m] =
//            (m<count) ? exp(10*C*rowscale[r]) : 0 -> bf16; rowsum ->
//            aux[r*64+slot]  (m-block loop, step 16)
// EPI_OUT  : XCD-swizzled rb; kel=meta[1]; outf = C*rowscale[r]+bias[n] (fp32)
// =============================================================================
#define EPI_QPROJ 0
#define EPI_MW    1
#define EPI_P     2
#define EPI_OUT   3

template<int EPI>
__global__ __launch_bounds__(256, 3)
void k_gemm_bt(const u16* __restrict__ A, const u16* __restrict__ B,
               int N, int K,
               const int* __restrict__ meta,
               float* __restrict__ outf, u16* __restrict__ outh,
               const float* __restrict__ bias,
               float* __restrict__ aux,
               const float* __restrict__ rowscale) {
  __shared__ u16 Ah[2][128 * 32];
  __shared__ u16 Bh[2][128 * 32];

  const int tid  = threadIdx.x;
  const int wave = tid >> 6, lane = tid & 63;
  const int wr = (wave >> 1) * 64;
  const int wc = (wave & 1) * 64;

  // t loops over the varying block dim; fixedb is the fixed one.
  int t0, t_end, t_step, kel, fixedb;
  if (EPI == EPI_QPROJ) {
    // rows = k (4 blocks, x), cols = r (128 blocks, y)
    fixedb = blockIdx.x; t0 = blockIdx.y; t_end = t0 + 1; t_step = 1; kel = K;
  } else if (EPI == EPI_MW) {
    fixedb = blockIdx.y; t0 = blockIdx.x; t_end = meta[1] >> 7; t_step = 16; kel = K;
  } else if (EPI == EPI_P) {
    // grid (16,128): all 16 m-blocks of an r-block on one XCD (qb+mkn ~4MB L2)
    int id = blockIdx.x + (blockIdx.y << 4);
    int xcd = id & 7, s = id >> 3;
    fixedb = xcd * 16 + (s >> 4);     // r col-block 0..127
    t0 = s & 15;                      // m row-block start
    t_end = meta[1] >> 7; t_step = 16; kel = K;
  } else { // EPI_OUT
    // grid (4,128): the 4 col-blocks of a row-block on one XCD
    int id = blockIdx.x + (blockIdx.y << 2);
    int xcd = id & 7, s = id >> 3;
    fixedb = xcd * 16 + (s >> 2);     // r row-block
    t0 = s & 3; t_end = t0 + 1; t_step = 1; kel = meta[1];
  }
  const int kiters = kel >> 5;

  // staging lane map: row = lane&15 within a 16-row slab, 32-col chunk = lane>>4
  const int srow   = lane & 15;
  const int schunk = lane >> 4;
  const int lds_off = schunk * 128 + srow * 8;    // within a 512-u16 slab

  const int fr = lane & 15;                       // fragment row/col within 16
  const int fbase = (lane >> 4) * 128 + fr * 8;   // LDS fragment offset
  const int g = lane >> 4;

  const char* Ac = (const char*)A;
  const char* Bc = (const char*)B;

  for (int t = t0; t < t_end; t += t_step) {
    const int row0 = ((EPI == EPI_P) ? t : fixedb) << 7;
    const int col0 = ((EPI == EPI_P) ? fixedb : t) << 7;
    __syncthreads();                              // guard LDS reuse across t

    uint32_t aB[2], bB[2];                        // byte offsets (fit u32)
    #pragma unroll
    for (int s2 = 0; s2 < 2; ++s2) {
      aB[s2] = (uint32_t)(((size_t)(row0 + (wave + s2 * 4) * 16 + srow) * (size_t)K
                           + (size_t)(schunk * 8)) * 2u);
      bB[s2] = (uint32_t)(((size_t)(col0 + (wave + s2 * 4) * 16 + srow) * (size_t)K
                           + (size_t)(schunk * 8)) * 2u);
    }

    f32x4 acc[4][4];
    const f32x4 z = {0.0f, 0.0f, 0.0f, 0.0f};
    #pragma unroll
    for (int i = 0; i < 4; ++i)
      #pragma unroll
      for (int j = 0; j < 4; ++j) acc[i][j] = z;

    bf16x8 rA[2], rB[2];
    auto gload = [&](int k0) {
      const uint32_t kb = (uint32_t)(k0 << 1);
      #pragma unroll
      for (int s2 = 0; s2 < 2; ++s2) rA[s2] = *(const bf16x8*)(Ac + aB[s2] + kb);
      #pragma unroll
      for (int s2 = 0; s2 < 2; ++s2) rB[s2] = *(const bf16x8*)(Bc + bB[s2] + kb);
    };

    gload(0);                                     // prologue (vmcnt exposed once)
    for (int it = 0; it < kiters; ++it) {
      const int cur = it & 1;
      #pragma unroll
      for (int s2 = 0; s2 < 2; ++s2)
        *(bf16x8*)&Ah[cur][(wave + s2 * 4) * 512 + lds_off] = rA[s2];
      #pragma unroll
      for (int s2 = 0; s2 < 2; ++s2)
        *(bf16x8*)&Bh[cur][(wave + s2 * 4) * 512 + lds_off] = rB[s2];
      if (it + 1 < kiters) gload((it + 1) << 5);  // next loads in flight
      __syncthreads();                            // lgkmcnt only — no vmcnt drain

      bf16x8 af[4], bfv[4];
      #pragma unroll
      for (int i = 0; i < 4; ++i)
        af[i] = *(const bf16x8*)&Ah[cur][((wr >> 4) + i) * 512 + fbase];
      #pragma unroll
      for (int j = 0; j < 4; ++j)
        bfv[j] = *(const bf16x8*)&Bh[cur][((wc >> 4) + j) * 512 + fbase];
      #pragma unroll
      for (int i = 0; i < 4; ++i)
        #pragma unroll
        for (int j = 0; j < 4; ++j)
          acc[i][j] = __builtin_amdgcn_mfma_f32_16x16x32_bf16(af[i], bfv[j], acc[i][j], 0, 0, 0);
    }

    // Epilogue. C/D layout per 16x16 tile: col = lane&15, row = (lane>>4)*4 + reg.
    if (EPI == EPI_QPROJ) {
      float sj[4] = {0.f, 0.f, 0.f, 0.f};
      #pragma unroll
      for (int i = 0; i < 4; ++i) {
        const int kb = row0 + wr + i * 16 + g * 4;          // 4 consecutive k
        const float4 bkv = *(const float4*)(bias + kb);
        #pragma unroll
        for (int j = 0; j < 4; ++j) {
          const size_t rcol = (size_t)(col0 + wc + j * 16 + fr);
          float v0 = acc[i][j][0] + bkv.x;
          float v1 = acc[i][j][1] + bkv.y;
          float v2 = acc[i][j][2] + bkv.z;
          float v3 = acc[i][j][3] + bkv.w;
          ushort4 st; st.x = f2b(v0); st.y = f2b(v1); st.z = f2b(v2); st.w = f2b(v3);
          *(ushort4*)(outh + rcol * H_DIM + kb) = st;       // packed 8B, [r][k]
          sj[j] += v0 * v0 + v1 * v1 + v2 * v2 + v3 * v3;
        }
      }
      const int slot = (row0 + wr) >> 6;                    // 0..7
      #pragma unroll
      for (int j = 0; j < 4; ++j) {
        float s = sj[j];
        s += __shfl_xor(s, 16, 64);
        s += __shfl_xor(s, 32, 64);
        if (lane < 16)
          aux[(size_t)(col0 + wc + j * 16 + lane) * 8 + slot] = s;
      }
    } else if (EPI == EPI_MW) {
      #pragma unroll
      for (int i = 0; i < 4; ++i) {
        #pragma unroll
        for (int r = 0; r < 4; ++r) {
          int grow = row0 + wr + i * 16 + g * 4 + r;
          #pragma unroll
          for (int j = 0; j < 4; ++j) {
            int gcol = col0 + wc + j * 16 + fr;
            outh[(size_t)grow * (size_t)N + gcol] = f2b(acc[i][j][r]);
          }
        }
      }
    } else if (EPI == EPI_P) {
      const int count = meta[0];
      float rq10[4];
      #pragma unroll
      for (int j = 0; j < 4; ++j)
        rq10[j] = rowscale[col0 + wc + j * 16 + fr] * 10.0f;
      float sj[4] = {0.f, 0.f, 0.f, 0.f};
      #pragma unroll
      for (int i = 0; i < 4; ++i) {
        const int mb = row0 + wr + i * 16 + g * 4;          // 4 consecutive m
        #pragma unroll
        for (int j = 0; j < 4; ++j) {
          const size_t rcol = (size_t)(col0 + wc + j * 16 + fr);
          float p0 = (mb + 0 < count) ? __expf(acc[i][j][0] * rq10[j]) : 0.0f;
          float p1 = (mb + 1 < count) ? __expf(acc[i][j][1] * rq10[j]) : 0.0f;
          float p2 = (mb + 2 < count) ? __expf(acc[i][j][2] * rq10[j]) : 0.0f;
          float p3 = (mb + 3 < count) ? __expf(acc[i][j][3] * rq10[j]) : 0.0f;
          ushort4 st; st.x = f2b(p0); st.y = f2b(p1); st.z = f2b(p2); st.w = f2b(p3);
          *(ushort4*)(outh + rcol * M_DIM + mb) = st;       // packed 8B, [r][m]
          sj[j] += (p0 + p1) + (p2 + p3);
        }
      }
      const int slot = (row0 + wr) >> 6;                    // 0..63
      #pragma unroll
      for (int j = 0; j < 4; ++j) {
        float s = sj[j];
        s += __shfl_xor(s, 16, 64);
        s += __shfl_xor(s, 32, 64);
        if (lane < 16)
          aux[(size_t)(col0 + wc + j * 16 + lane) * 64 + slot] = s;
      }
    } else {  // EPI_OUT
      float bv[4];
      #pragma unroll
      for (int j = 0; j < 4; ++j) bv[j] = bias[col0 + wc + j * 16 + fr];
      #pragma unroll
      for (int i = 0; i < 4; ++i) {
        #pragma unroll
        for (int r = 0; r < 4; ++r) {
          int grow = row0 + wr + i * 16 + g * 4 + r;
          float sc = rowscale[grow];
          #pragma unroll
          for (int j = 0; j < 4; ++j) {
            int gcol = col0 + wc + j * 16 + fr;
            outf[(size_t)grow * (size_t)N + gcol] = acc[i][j][r] * sc + bv[j];
          }
        }
      }
    }
  }
}

extern "C" void kernel_launch(void* const* d_in, const int* in_sizes, int n_in,
                              void* d_out, int out_size, void* d_ws, size_t ws_size,
                              hipStream_t stream) {
  const float* hidden = (const float*)d_in[0];   // [16384, 512]
  const float* mkeys  = (const float*)d_in[1];   // [4096, 512]
  const float* mvals  = (const float*)d_in[2];   // [4096, 512]
  const float* Wk     = (const float*)d_in[3];   // [512, 512]
  const float* bk     = (const float*)d_in[4];   // [512]
  const float* Wo     = (const float*)d_in[5];   // [512, 512]
  const float* bo     = (const float*)d_in[6];   // [512]
  const int*   usage  = (const int*)d_in[7];     // [4096]
  (void)in_sizes; (void)n_in; (void)out_size; (void)ws_size;

  char* ws = (char*)d_ws;
  // hb region [0,16MB): bf16 hidden during q-proj; dead afterwards ->
  // idx/meta overlay at [0,16448) and lpart overlay at [1MB,5MB).
  u16*   hb    = (u16*)(ws + 0);            //  16,777,216  hidden bf16 (early)
  int*   idx   = (int*)(ws + 0);            //      16,384  compacted->orig map (late)
  int*   meta  = (int*)(ws + 16384);        //          16  {count, K_eff, K/32, K/128}
  float* lpart = (float*)(ws + 1048576);    //   4,194,304  row-sum partials [16384,64] (late)
  u16*   wkb   = (u16*)(ws + 16777216);     //     524,288  Wk bf16
  u16*   wob   = (u16*)(ws + 17301504);     //     524,288  Wo bf16
  u16*   mkn   = (u16*)(ws + 17825792);     //   4,194,304  compacted normalized keys bf16
  u16*   mv_c  = (u16*)(ws + 22020096);     //   4,194,304  compacted mvals bf16
  u16*   qb    = (u16*)(ws + 26214400);     //  16,777,216  q bf16 (unnormalized, +bk) [r][k]
  u16*   MWt   = (u16*)(ws + 42991616);     //   4,194,304  (mvals@Wo^T)^T bf16 [512,4096]
  u16*   P     = (u16*)(ws + 47185920);     // 134,217,728  exp-scores bf16 [16384,4096]
  float* qss   = (float*)(ws + 47185920);   //     524,288  q sumsq partials [16384,8]
                                            //              (overlays P; dead before P written)
  float* rsqQ  = (float*)(ws + 181665792);  //      65,536  rsqrt(|q|^2+eps) [16384]
  float* linv  = (float*)(ws + 183828480);  //      65,536  1/rowsum [16384]
  // total: 183,894,016 bytes (unchanged)

  // casts
  k_f2bf<<<8192, 256, 0, stream>>>(hidden, hb, 2097152);
  k_f2bf_ww<<<512, 256, 0, stream>>>(Wk, Wo, wkb, wob);

  // q[r,k] = hidden @ Wk^T + bk, computed swapped: C[k,r] = Wk . hb^T
  // -> bf16 qb[r][k] + per-r sumsq partials (8 slots)
  k_gemm_bt<EPI_QPROJ><<<dim3(4, 128), 256, 0, stream>>>(wkb, hb, 512, 512,
      nullptr, nullptr, qb, bk, qss, nullptr);
  k_rsq<<<64, 256, 0, stream>>>(qss, rsqQ);

  // compaction of the memory bank (hb now dead)
  k_compact<<<1, 256, 0, stream>>>(usage, idx, meta);
  k_gather_both<<<1024, 256, 0, stream>>>(mkeys, mvals, idx, meta, mkn, mv_c);

  // MWt[h, m] = sum_v Wo[h,v] * mvals_c[m,v]  (Wo folded into V)
  k_gemm_bt<EPI_MW><<<dim3(16, 4), 256, 0, stream>>>(wob, mv_c, M_DIM, 512,
      meta, nullptr, MWt, nullptr, nullptr, nullptr);

  // P[r,m] = exp(10 * (qb @ mkn^T) * rsqQ[r]) over active slots, computed
  // swapped: C[m,r] = mkn . qb^T; packed stores into [r][m]; rowsum partials
  k_gemm_bt<EPI_P><<<dim3(16, 128), 256, 0, stream>>>(mkn, qb, M_DIM, 512,
      meta, nullptr, P, nullptr, lpart, rsqQ);
  k_reduce_l<<<64, 256, 0, stream>>>(lpart, linv, meta);

  // out = (P @ MWt^T) * linv[r] + bo   (fp32, direct to d_out)
  k_gemm_bt<EPI_OUT><<<dim3(4, 128), 256, 0, stream>>>(P, MWt, 512, M_DIM,
      meta, (float*)d_out, nullptr, bo, nullptr, linv);
}

// Round 2
// 255.083 us; speedup vs baseline: 1.1464x; 1.1464x over previous
//
#include <hip/hip_runtime.h>
#include <cstdint>
#include <cstddef>

// Problem constants: B=8, S=2048, H=512, M=4096 -> R = B*S = 16384 rows.
#define H_DIM   512
#define M_DIM   4096

typedef unsigned short u16;
typedef short bf16x8 __attribute__((ext_vector_type(8)));   // 8 bf16 in 4 VGPRs
typedef float f32x4  __attribute__((ext_vector_type(4)));

// fp32 -> bf16 round-to-nearest-even
__device__ __forceinline__ u16 f2b(float f) {
  union { float f; uint32_t u; } v; v.f = f;
  uint32_t u = v.u + (0x7FFFu + ((v.u >> 16) & 1u));
  return (u16)(u >> 16);
}

// ---------------- elementwise fp32 -> bf16 (n4 = n/4 float4 groups) ----------
__global__ void k_f2bf(const float* __restrict__ in, u16* __restrict__ out, int n4) {
  int i = blockIdx.x * blockDim.x + threadIdx.x;
  if (i < n4) {
    float4 v = ((const float4*)in)[i];
    ushort4 o;
    o.x = f2b(v.x); o.y = f2b(v.y); o.z = f2b(v.z); o.w = f2b(v.w);
    ((ushort4*)out)[i] = o;
  }
}

// ---- both weight casts in one launch: 512 blocks x 256 thr, 2x 65536 f4 -----
__global__ void k_f2bf_ww(const float* __restrict__ wk, const float* __restrict__ wo,
                          u16* __restrict__ owk, u16* __restrict__ owo) {
  int i = blockIdx.x * blockDim.x + threadIdx.x;
  const float* src = (i < 65536) ? wk : wo;
  u16* dst = (i < 65536) ? owk : owo;
  int j = i & 65535;
  float4 v = ((const float4*)src)[j];
  ushort4 o;
  o.x = f2b(v.x); o.y = f2b(v.y); o.z = f2b(v.z); o.w = f2b(v.w);
  ((ushort4*)dst)[j] = o;
}

// ---- compaction: scan usage[4096] -> idx map + meta -------------------------
// meta[0]=count, meta[1]=K_eff=round128(count), meta[2]=K_eff/32, meta[3]=K_eff/128
__global__ void k_compact(const int* __restrict__ usage, int* __restrict__ idx,
                          int* __restrict__ meta) {
  __shared__ int cnt[256];
  int t = threadIdx.x;
  int base = t * 16;
  int c = 0;
  #pragma unroll
  for (int i = 0; i < 16; ++i) c += (usage[base + i] > 0) ? 1 : 0;
  cnt[t] = c;
  __syncthreads();
  for (int d = 1; d < 256; d <<= 1) {           // inclusive Hillis-Steele scan
    int v = (t >= d) ? cnt[t - d] : 0;
    __syncthreads();
    cnt[t] += v;
    __syncthreads();
  }
  int pos = cnt[t] - c;                          // exclusive prefix
  for (int i = 0; i < 16; ++i)
    if (usage[base + i] > 0) idx[pos++] = base + i;
  if (t == 0) {
    int total = cnt[255];
    int keff = ((total + 127) >> 7) << 7;        // 128-granular padding
    meta[0] = total; meta[1] = keff; meta[2] = keff >> 5; meta[3] = keff >> 7;
  }
}

// ---- gather both: keys (L2-normalized) AND vals (plain) -> compacted bf16 ---
// Zero-pads ALL rows j in [count, 4096) (needed: 256-row tiles may read them).
__global__ void k_gather_both(const float* __restrict__ keys, const float* __restrict__ vals,
                              const int* __restrict__ idx, const int* __restrict__ meta,
                              u16* __restrict__ okeys, u16* __restrict__ ovals) {
  int j    = blockIdx.x * 4 + (threadIdx.x >> 6);
  int lane = threadIdx.x & 63;
  int count = meta[0];
  ushort4* kp = (ushort4*)(okeys + (size_t)j * H_DIM);
  ushort4* vp = (ushort4*)(ovals + (size_t)j * H_DIM);
  if (j >= count) {                 // wave-uniform
    ushort4 z = {0, 0, 0, 0};
    kp[lane] = z; kp[lane + 64] = z;
    vp[lane] = z; vp[lane + 64] = z;
    return;
  }
  int src = idx[j];
  // keys: normalize
  const float4* rp = (const float4*)(keys + (size_t)src * H_DIM);
  float4 a = rp[lane];
  float4 b = rp[lane + 64];
  float ss = a.x*a.x + a.y*a.y + a.z*a.z + a.w*a.w
           + b.x*b.x + b.y*b.y + b.z*b.z + b.w*b.w;
  #pragma unroll
  for (int d = 1; d < 64; d <<= 1) ss += __shfl_xor(ss, d, 64);
  float s = rsqrtf(ss + 1e-6f);
  ushort4 oa, ob;
  oa.x = f2b(a.x*s); oa.y = f2b(a.y*s); oa.z = f2b(a.z*s); oa.w = f2b(a.w*s);
  ob.x = f2b(b.x*s); ob.y = f2b(b.y*s); ob.z = f2b(b.z*s); ob.w = f2b(b.w*s);
  kp[lane]      = oa;
  kp[lane + 64] = ob;
  // vals: plain cast
  const float4* vr = (const float4*)(vals + (size_t)src * H_DIM);
  float4 c0 = vr[lane];
  float4 c1 = vr[lane + 64];
  ushort4 va, vb;
  va.x = f2b(c0.x); va.y = f2b(c0.y); va.z = f2b(c0.z); va.w = f2b(c0.w);
  vb.x = f2b(c1.x); vb.y = f2b(c1.y); vb.z = f2b(c1.z); vb.w = f2b(c1.w);
  vp[lane]      = va;
  vp[lane + 64] = vb;
}

// ---- rsqQ[r] = rsqrt(sum of 8 qss partials + eps) ---------------------------
__global__ void k_rsq(const float* __restrict__ qss, float* __restrict__ rsq) {
  int r = blockIdx.x * blockDim.x + threadIdx.x;
  float s = 0.0f;
  #pragma unroll
  for (int i = 0; i < 8; ++i) s += qss[(size_t)r * 8 + i];
  rsq[r] = rsqrtf(s + 1e-6f);
}

// ---- reduce partial row sums -> reciprocal (n = meta[1]/64 64-chunks) -------
__global__ void k_reduce_l(const float* __restrict__ lpart, float* __restrict__ linv,
                           const int* __restrict__ meta) {
  int r = blockIdx.x * blockDim.x + threadIdx.x;
  int n = meta[1] >> 6;
  float s = 0.0f;
  for (int i = 0; i < n; ++i) s += lpart[(size_t)r * 64 + i];
  linv[r] = 1.0f / s;
}

// =============================================================================
// Small-tile BT GEMM (128x128, 256 thr, 4 waves) — kept for QPROJ and MW only.
// =============================================================================
#define EPI_QPROJ 0
#define EPI_MW    1

template<int EPI>
__global__ __launch_bounds__(256, 3)
void k_gemm_bt(const u16* __restrict__ A, const u16* __restrict__ B,
               int N, int K,
               const int* __restrict__ meta,
               float* __restrict__ outf, u16* __restrict__ outh,
               const float* __restrict__ bias,
               float* __restrict__ aux,
               const float* __restrict__ rowscale) {
  __shared__ u16 Ah[2][128 * 32];
  __shared__ u16 Bh[2][128 * 32];

  const int tid  = threadIdx.x;
  const int wave = tid >> 6, lane = tid & 63;
  const int wr = (wave >> 1) * 64;
  const int wc = (wave & 1) * 64;

  int t0, t_end, t_step, kel, fixedb;
  if (EPI == EPI_QPROJ) {
    fixedb = blockIdx.x; t0 = blockIdx.y; t_end = t0 + 1; t_step = 1; kel = K;
  } else { // EPI_MW
    fixedb = blockIdx.y; t0 = blockIdx.x; t_end = meta[1] >> 7; t_step = 16; kel = K;
  }
  const int kiters = kel >> 5;

  const int srow   = lane & 15;
  const int schunk = lane >> 4;
  const int lds_off = schunk * 128 + srow * 8;    // within a 512-u16 slab

  const int fr = lane & 15;
  const int fbase = (lane >> 4) * 128 + fr * 8;
  const int g = lane >> 4;

  const char* Ac = (const char*)A;
  const char* Bc = (const char*)B;

  for (int t = t0; t < t_end; t += t_step) {
    const int row0 = fixedb << 7;
    const int col0 = t << 7;
    __syncthreads();                              // guard LDS reuse across t

    uint32_t aB[2], bB[2];
    #pragma unroll
    for (int s2 = 0; s2 < 2; ++s2) {
      aB[s2] = (uint32_t)(((size_t)(row0 + (wave + s2 * 4) * 16 + srow) * (size_t)K
                           + (size_t)(schunk * 8)) * 2u);
      bB[s2] = (uint32_t)(((size_t)(col0 + (wave + s2 * 4) * 16 + srow) * (size_t)K
                           + (size_t)(schunk * 8)) * 2u);
    }

    f32x4 acc[4][4];
    const f32x4 z = {0.0f, 0.0f, 0.0f, 0.0f};
    #pragma unroll
    for (int i = 0; i < 4; ++i)
      #pragma unroll
      for (int j = 0; j < 4; ++j) acc[i][j] = z;

    bf16x8 rA[2], rB[2];
    auto gload = [&](int k0) {
      const uint32_t kb = (uint32_t)(k0 << 1);
      #pragma unroll
      for (int s2 = 0; s2 < 2; ++s2) rA[s2] = *(const bf16x8*)(Ac + aB[s2] + kb);
      #pragma unroll
      for (int s2 = 0; s2 < 2; ++s2) rB[s2] = *(const bf16x8*)(Bc + bB[s2] + kb);
    };

    gload(0);
    for (int it = 0; it < kiters; ++it) {
      const int cur = it & 1;
      #pragma unroll
      for (int s2 = 0; s2 < 2; ++s2)
        *(bf16x8*)&Ah[cur][(wave + s2 * 4) * 512 + lds_off] = rA[s2];
      #pragma unroll
      for (int s2 = 0; s2 < 2; ++s2)
        *(bf16x8*)&Bh[cur][(wave + s2 * 4) * 512 + lds_off] = rB[s2];
      if (it + 1 < kiters) gload((it + 1) << 5);
      __syncthreads();                            // lgkmcnt only — no vmcnt drain

      bf16x8 af[4], bfv[4];
      #pragma unroll
      for (int i = 0; i < 4; ++i)
        af[i] = *(const bf16x8*)&Ah[cur][((wr >> 4) + i) * 512 + fbase];
      #pragma unroll
      for (int j = 0; j < 4; ++j)
        bfv[j] = *(const bf16x8*)&Bh[cur][((wc >> 4) + j) * 512 + fbase];
      #pragma unroll
      for (int i = 0; i < 4; ++i)
        #pragma unroll
        for (int j = 0; j < 4; ++j)
          acc[i][j] = __builtin_amdgcn_mfma_f32_16x16x32_bf16(af[i], bfv[j], acc[i][j], 0, 0, 0);
    }

    // Epilogue. C/D layout per 16x16 tile: col = lane&15, row = (lane>>4)*4 + reg.
    if (EPI == EPI_QPROJ) {
      float sj[4] = {0.f, 0.f, 0.f, 0.f};
      #pragma unroll
      for (int i = 0; i < 4; ++i) {
        const int kb = row0 + wr + i * 16 + g * 4;          // 4 consecutive k
        const float4 bkv = *(const float4*)(bias + kb);
        #pragma unroll
        for (int j = 0; j < 4; ++j) {
          const size_t rcol = (size_t)(col0 + wc + j * 16 + fr);
          float v0 = acc[i][j][0] + bkv.x;
          float v1 = acc[i][j][1] + bkv.y;
          float v2 = acc[i][j][2] + bkv.z;
          float v3 = acc[i][j][3] + bkv.w;
          ushort4 st; st.x = f2b(v0); st.y = f2b(v1); st.z = f2b(v2); st.w = f2b(v3);
          *(ushort4*)(outh + rcol * H_DIM + kb) = st;       // packed 8B, [r][k]
          sj[j] += v0 * v0 + v1 * v1 + v2 * v2 + v3 * v3;
        }
      }
      const int slot = (row0 + wr) >> 6;                    // 0..7
      #pragma unroll
      for (int j = 0; j < 4; ++j) {
        float s = sj[j];
        s += __shfl_xor(s, 16, 64);
        s += __shfl_xor(s, 32, 64);
        if (lane < 16)
          aux[(size_t)(col0 + wc + j * 16 + lane) * 8 + slot] = s;
      }
    } else { // EPI_MW
      #pragma unroll
      for (int i = 0; i < 4; ++i) {
        #pragma unroll
        for (int r = 0; r < 4; ++r) {
          int grow = row0 + wr + i * 16 + g * 4 + r;
          #pragma unroll
          for (int j = 0; j < 4; ++j) {
            int gcol = col0 + wc + j * 16 + fr;
            outh[(size_t)grow * (size_t)N + gcol] = f2b(acc[i][j][r]);
          }
        }
      }
    }
  }
}

// =============================================================================
// Big-tile BT GEMM: 512 threads = 8 waves (wave grid 2Mx4N), BK=32,
// reg-staged single-barrier double buffer (same hazard structure as the
// verified 128x128 kernel — one __syncthreads per K-step, no vmcnt drain).
//
// EPI2_P  : A=mkn (BM=256 m-rows), B=qb (256 r), K=512 static. C[m][r]
//           (swapped). Per-wave 128m x 64r, acc[8][4]. Epilogue: P[r][m] =
//           (m<count) ? exp(10*C*rsqQ[r]) : 0 packed ushort4; per-wave
//           in-register row sums -> lpart slot pair (sum, 0).
// EPI2_OUT: A=MWt (BM=128 h-rows), B=P (256 r), K=meta[1] runtime. C[h][r]
//           (swapped). Per-wave 64h x 64r, acc[4][4]. Epilogue: out[r][h] =
//           C*linv[r]+bo[h], coalesced float4 stores.
//
// LDS layout (proven conflict-free): per K-slab of 32 cols, rows stored as
// 16-row sub-blocks [chunk(4)][row(16)][8 elem]; linear in 16B units where
// unit = slab*64 + chunk*16 + row; staging thread t writes unit t (+512).
// Fragment read: lane -> unit slab*64 + (lane>>4)*16 + (lane&15): 64 distinct
// 16B slots per wave -> zero bank conflicts (measured 0 in the 128x128 core).
//
// Per K-step per wave: EPI2_P: 12 ds_read_b128 -> 32 MFMA (2.67 MFMA/read);
// EPI2_OUT: 8 -> 16. MFMA-dominant per SIMD (2 waves: ~320 cyc MFMA vs
// ~290 cyc LDS reads), vs 1.5 MFMA/read in the 128x128 core.
// =============================================================================
#define EPI2_P   0
#define EPI2_OUT 1

template<int EPI>
__global__ __launch_bounds__(512, 2)
void k_gemm2(const u16* __restrict__ A, const u16* __restrict__ B,
             const int* __restrict__ meta,
             float* __restrict__ outf, u16* __restrict__ outh,
             const float* __restrict__ bias,
             float* __restrict__ aux,
             const float* __restrict__ rowscale) {
  constexpr int BM  = (EPI == EPI2_P) ? 256 : 128;  // A rows per tile
  constexpr int MF  = BM / 32;                      // m-frags per wave: 8 / 4
  constexpr int NF  = 4;                            // r-frags per wave (64/16)
  constexpr int NLA = BM / 128;                     // A stage loads/thread
  constexpr int NLB = 2;                            // B stage loads/thread

  __shared__ u16 Ah[2][BM * 32];
  __shared__ u16 Bh[2][256 * 32];

  const int tid  = threadIdx.x;
  const int wave = tid >> 6, lane = tid & 63;
  const int wave_m = wave >> 2, wave_n = wave & 3;
  const int wm0 = wave_m * (BM >> 1);               // wave m-offset (0/128 or 0/64)
  const int wn0 = wave_n * 64;                      // wave r-offset
  const int fr  = lane & 15, g = lane >> 4;
  const int fbase = g * 128 + fr * 8;               // fragment LDS offset (u16)

  int m0, r0, kel;
  if (EPI == EPI2_P) {
    // grid (16,64): XCD-swizzled; all 16 m-blocks of 8 r-blocks per XCD
    int id = blockIdx.x + (blockIdx.y << 4);
    int xcd = id & 7, s = id >> 3;
    r0 = (xcd * 8 + (s >> 4)) << 8;
    m0 = (s & 15) << 8;
    if (m0 >= meta[1]) return;                      // inactive m-block
    kel = 512;
  } else {
    // grid (4,64): XCD-swizzled; the 4 h-blocks of 8 r-blocks per XCD
    int id = blockIdx.x + (blockIdx.y << 2);
    int xcd = id & 7, s = id >> 3;
    r0 = (xcd * 8 + (s >> 2)) << 8;
    m0 = (s & 3) << 7;                              // h0
    kel = meta[1];
  }
  const int kiters = kel >> 5;
  const int kstr = (EPI == EPI2_P) ? 512 : M_DIM;   // row stride of A and B

  // staging: thread t, load s2 -> 16B unit (t + s2*512)
  const char* Ac = (const char*)A;
  const char* Bc = (const char*)B;
  uint32_t aB[NLA], bB[NLB];
  #pragma unroll
  for (int s2 = 0; s2 < NLA; ++s2) {
    int unit = tid + s2 * 512;
    int row = ((unit >> 6) << 4) + (unit & 15);
    int kch = (unit >> 4) & 3;
    aB[s2] = (uint32_t)(((size_t)(m0 + row) * (size_t)kstr + (size_t)(kch * 8)) * 2u);
  }
  #pragma unroll
  for (int s2 = 0; s2 < NLB; ++s2) {
    int unit = tid + s2 * 512;
    int row = ((unit >> 6) << 4) + (unit & 15);
    int kch = (unit >> 4) & 3;
    bB[s2] = (uint32_t)(((size_t)(r0 + row) * (size_t)kstr + (size_t)(kch * 8)) * 2u);
  }

  f32x4 acc[MF][NF];
  const f32x4 z = {0.0f, 0.0f, 0.0f, 0.0f};
  #pragma unroll
  for (int i = 0; i < MF; ++i)
    #pragma unroll
    for (int j = 0; j < NF; ++j) acc[i][j] = z;

  bf16x8 rA[NLA], rB[NLB];
  auto gload = [&](int k0) {
    const uint32_t kb = (uint32_t)(k0 << 1);
    #pragma unroll
    for (int s2 = 0; s2 < NLA; ++s2) rA[s2] = *(const bf16x8*)(Ac + aB[s2] + kb);
    #pragma unroll
    for (int s2 = 0; s2 < NLB; ++s2) rB[s2] = *(const bf16x8*)(Bc + bB[s2] + kb);
  };

  gload(0);                                         // prologue
  for (int it = 0; it < kiters; ++it) {
    const int cur = it & 1;
    #pragma unroll
    for (int s2 = 0; s2 < NLA; ++s2)
      *(bf16x8*)&Ah[cur][(tid + s2 * 512) * 8] = rA[s2];
    #pragma unroll
    for (int s2 = 0; s2 < NLB; ++s2)
      *(bf16x8*)&Bh[cur][(tid + s2 * 512) * 8] = rB[s2];
    if (it + 1 < kiters) gload((it + 1) << 5);      // next loads in flight
    __syncthreads();                                // lgkmcnt only

    bf16x8 af[MF], bfv[NF];
    #pragma unroll
    for (int i = 0; i < MF; ++i)
      af[i] = *(const bf16x8*)&Ah[cur][((wm0 >> 4) + i) * 512 + fbase];
    #pragma unroll
    for (int j = 0; j < NF; ++j)
      bfv[j] = *(const bf16x8*)&Bh[cur][((wn0 >> 4) + j) * 512 + fbase];
    #pragma unroll
    for (int i = 0; i < MF; ++i)
      #pragma unroll
      for (int j = 0; j < NF; ++j)
        acc[i][j] = __builtin_amdgcn_mfma_f32_16x16x32_bf16(af[i], bfv[j], acc[i][j], 0, 0, 0);
  }

  // Epilogues. C/D layout per 16x16 tile: col = lane&15, row = (lane>>4)*4 + reg.
  if (EPI == EPI2_P) {
    const int count = meta[0];
    float rq10[NF];
    #pragma unroll
    for (int j = 0; j < NF; ++j)
      rq10[j] = rowscale[r0 + wn0 + j * 16 + fr] * 10.0f;
    float sj[NF] = {0.f, 0.f, 0.f, 0.f};
    #pragma unroll
    for (int i = 0; i < MF; ++i) {
      const int mb = m0 + wm0 + i * 16 + g * 4;     // 4 consecutive m
      #pragma unroll
      for (int j = 0; j < NF; ++j) {
        const size_t rr = (size_t)(r0 + wn0 + j * 16 + fr);
        float p0 = (mb + 0 < count) ? __expf(acc[i][j][0] * rq10[j]) : 0.0f;
        float p1 = (mb + 1 < count) ? __expf(acc[i][j][1] * rq10[j]) : 0.0f;
        float p2 = (mb + 2 < count) ? __expf(acc[i][j][2] * rq10[j]) : 0.0f;
        float p3 = (mb + 3 < count) ? __expf(acc[i][j][3] * rq10[j]) : 0.0f;
        ushort4 st; st.x = f2b(p0); st.y = f2b(p1); st.z = f2b(p2); st.w = f2b(p3);
        *(ushort4*)(outh + rr * M_DIM + mb) = st;   // packed 8B, [r][m]
        sj[j] += (p0 + p1) + (p2 + p3);
      }
    }
    // wave covers m-range [m0+wm0, +128) -> slot pair (base, base+1)
    const int slot = (m0 + wm0) >> 6;
    #pragma unroll
    for (int j = 0; j < NF; ++j) {
      float s = sj[j];
      s += __shfl_xor(s, 16, 64);
      s += __shfl_xor(s, 32, 64);
      if (lane < 16) {
        const size_t rr = (size_t)(r0 + wn0 + j * 16 + lane);
        aux[rr * 64 + slot]     = s;
        aux[rr * 64 + slot + 1] = 0.0f;
      }
    }
  } else { // EPI2_OUT
    float scl[NF];
    #pragma unroll
    for (int j = 0; j < NF; ++j)
      scl[j] = rowscale[r0 + wn0 + j * 16 + fr];    // linv per r
    #pragma unroll
    for (int i = 0; i < MF; ++i) {
      const int hb = m0 + wm0 + i * 16 + g * 4;     // 4 consecutive h
      const float4 bv = *(const float4*)(bias + hb);
      #pragma unroll
      for (int j = 0; j < NF; ++j) {
        const size_t rr = (size_t)(r0 + wn0 + j * 16 + fr);
        float4 o;
        o.x = acc[i][j][0] * scl[j] + bv.x;
        o.y = acc[i][j][1] * scl[j] + bv.y;
        o.z = acc[i][j][2] * scl[j] + bv.z;
        o.w = acc[i][j][3] * scl[j] + bv.w;
        *(float4*)(outf + rr * H_DIM + hb) = o;     // coalesced 16B store
      }
    }
  }
}

extern "C" void kernel_launch(void* const* d_in, const int* in_sizes, int n_in,
                              void* d_out, int out_size, void* d_ws, size_t ws_size,
                              hipStream_t stream) {
  const float* hidden = (const float*)d_in[0];   // [16384, 512]
  const float* mkeys  = (const float*)d_in[1];   // [4096, 512]
  const float* mvals  = (const float*)d_in[2];   // [4096, 512]
  const float* Wk     = (const float*)d_in[3];   // [512, 512]
  const float* bk     = (const float*)d_in[4];   // [512]
  const float* Wo     = (const float*)d_in[5];   // [512, 512]
  const float* bo     = (const float*)d_in[6];   // [512]
  const int*   usage  = (const int*)d_in[7];     // [4096]
  (void)in_sizes; (void)n_in; (void)out_size; (void)ws_size;

  char* ws = (char*)d_ws;
  // hb region [0,16MB): bf16 hidden during q-proj; dead afterwards ->
  // idx/meta overlay at [0,16448) and lpart overlay at [1MB,5MB).
  u16*   hb    = (u16*)(ws + 0);            //  16,777,216  hidden bf16 (early)
  int*   idx   = (int*)(ws + 0);            //      16,384  compacted->orig map (late)
  int*   meta  = (int*)(ws + 16384);        //          16  {count, K_eff, K/32, K/128}
  float* lpart = (float*)(ws + 1048576);    //   4,194,304  row-sum partials [16384,64] (late)
  u16*   wkb   = (u16*)(ws + 16777216);     //     524,288  Wk bf16
  u16*   wob   = (u16*)(ws + 17301504);     //     524,288  Wo bf16
  u16*   mkn   = (u16*)(ws + 17825792);     //   4,194,304  compacted normalized keys bf16
  u16*   mv_c  = (u16*)(ws + 22020096);     //   4,194,304  compacted mvals bf16
  u16*   qb    = (u16*)(ws + 26214400);     //  16,777,216  q bf16 (unnormalized, +bk) [r][k]
  u16*   MWt   = (u16*)(ws + 42991616);     //   4,194,304  (mvals@Wo^T)^T bf16 [512,4096]
  u16*   P     = (u16*)(ws + 47185920);     // 134,217,728  exp-scores bf16 [16384,4096]
  float* qss   = (float*)(ws + 47185920);   //     524,288  q sumsq partials [16384,8]
                                            //              (overlays P; dead before P written)
  float* rsqQ  = (float*)(ws + 181665792);  //      65,536  rsqrt(|q|^2+eps) [16384]
  float* linv  = (float*)(ws + 183828480);  //      65,536  1/rowsum [16384]
  // total: 183,894,016 bytes (unchanged)

  // casts
  k_f2bf<<<8192, 256, 0, stream>>>(hidden, hb, 2097152);
  k_f2bf_ww<<<512, 256, 0, stream>>>(Wk, Wo, wkb, wob);

  // q[r,k] = hidden @ Wk^T + bk, computed swapped: C[k,r] = Wk . hb^T
  k_gemm_bt<EPI_QPROJ><<<dim3(4, 128), 256, 0, stream>>>(wkb, hb, 512, 512,
      nullptr, nullptr, qb, bk, qss, nullptr);
  k_rsq<<<64, 256, 0, stream>>>(qss, rsqQ);

  // compaction of the memory bank (hb now dead)
  k_compact<<<1, 256, 0, stream>>>(usage, idx, meta);
  k_gather_both<<<1024, 256, 0, stream>>>(mkeys, mvals, idx, meta, mkn, mv_c);

  // MWt[h, m] = sum_v Wo[h,v] * mvals_c[m,v]  (Wo folded into V)
  k_gemm_bt<EPI_MW><<<dim3(16, 4), 256, 0, stream>>>(wob, mv_c, M_DIM, 512,
      meta, nullptr, MWt, nullptr, nullptr, nullptr);

  // P[r,m] = exp(10 * (qb @ mkn^T) * rsqQ[r]) — 256x256 tile, swapped C[m][r]
  k_gemm2<EPI2_P><<<dim3(16, 64), 512, 0, stream>>>(mkn, qb, meta,
      nullptr, P, nullptr, lpart, rsqQ);
  k_reduce_l<<<64, 256, 0, stream>>>(lpart, linv, meta);

  // out[r,h] = (P @ MWt^T)*linv[r] + bo — 128x256 tile, swapped C[h][r]
  k_gemm2<EPI2_OUT><<<dim3(4, 64), 512, 0, stream>>>(MWt, P, meta,
      (float*)d_out, nullptr, bo, nullptr, linv);
}